// Round 1
// baseline (1878.482 us; speedup 1.0000x reference)
//
#include <hip/hip_runtime.h>
#include <hip/hip_bf16.h>

#define N_NODES 50000
#define N_EDGES 800000
#define LATDIM 128
#define HEAD 4

// ---------------------------------------------------------------------------
// Kernel 1: node projections  P = embeds @ W  for W in {qW, kW, vW}
// block = 256 threads = 128 cols x 2 row-groups; each row-group does 4 rows
// per pass (8 rows/block/pass, 8 passes -> 64 rows per block).
// W (64 KB) staged in LDS; each LDS read of W[d][c] reused across 4 rows.
// grid = (ceil(N/64), 3)
// ---------------------------------------------------------------------------
__global__ __launch_bounds__(256) void proj_kernel(
    const float* __restrict__ embeds,
    const float* __restrict__ qW,
    const float* __restrict__ kW,
    const float* __restrict__ vW,
    float* __restrict__ Pbase)  // Q | K | V contiguous, each N_NODES*128
{
    __shared__ float Wl[128 * 128];

    const int which = blockIdx.y;
    const float* W = (which == 0) ? qW : (which == 1) ? kW : vW;
    float* out = Pbase + (size_t)which * N_NODES * LATDIM;

    // Stage W into LDS (16384 floats = 4096 float4, 16 per thread, coalesced)
    const float4* W4 = (const float4*)W;
    float4* Wl4 = (float4*)Wl;
#pragma unroll
    for (int i = 0; i < 16; ++i)
        Wl4[threadIdx.x + 256 * i] = W4[threadIdx.x + 256 * i];
    __syncthreads();

    const int c  = threadIdx.x & 127;   // output column
    const int rg = threadIdx.x >> 7;    // row-group 0/1
    const int row0 = blockIdx.x * 64;

    for (int pass = 0; pass < 8; ++pass) {
        const int rbase = row0 + pass * 8 + rg * 4;
        // clamp row indices for loads; stores are guarded
        int r0 = rbase + 0, r1 = rbase + 1, r2 = rbase + 2, r3 = rbase + 3;
        int l0 = r0 < N_NODES ? r0 : N_NODES - 1;
        int l1 = r1 < N_NODES ? r1 : N_NODES - 1;
        int l2 = r2 < N_NODES ? r2 : N_NODES - 1;
        int l3 = r3 < N_NODES ? r3 : N_NODES - 1;
        const float4* e0 = (const float4*)(embeds + (size_t)l0 * LATDIM);
        const float4* e1 = (const float4*)(embeds + (size_t)l1 * LATDIM);
        const float4* e2 = (const float4*)(embeds + (size_t)l2 * LATDIM);
        const float4* e3 = (const float4*)(embeds + (size_t)l3 * LATDIM);

        float a0 = 0.f, a1 = 0.f, a2 = 0.f, a3 = 0.f;
#pragma unroll 8
        for (int d4 = 0; d4 < 32; ++d4) {
            float4 x0 = e0[d4];
            float4 x1 = e1[d4];
            float4 x2 = e2[d4];
            float4 x3 = e3[d4];
            float w0 = Wl[(d4 * 4 + 0) * 128 + c];
            float w1 = Wl[(d4 * 4 + 1) * 128 + c];
            float w2 = Wl[(d4 * 4 + 2) * 128 + c];
            float w3 = Wl[(d4 * 4 + 3) * 128 + c];
            a0 += x0.x * w0 + x0.y * w1 + x0.z * w2 + x0.w * w3;
            a1 += x1.x * w0 + x1.y * w1 + x1.z * w2 + x1.w * w3;
            a2 += x2.x * w0 + x2.y * w1 + x2.z * w2 + x2.w * w3;
            a3 += x3.x * w0 + x3.y * w1 + x3.z * w2 + x3.w * w3;
        }
        if (r0 < N_NODES) out[(size_t)r0 * LATDIM + c] = a0;
        if (r1 < N_NODES) out[(size_t)r1 * LATDIM + c] = a1;
        if (r2 < N_NODES) out[(size_t)r2 * LATDIM + c] = a2;
        if (r3 < N_NODES) out[(size_t)r3 * LATDIM + c] = a3;
    }
}

// ---------------------------------------------------------------------------
// Kernel 2: per-edge attention logits -> exp -> scatter-add denominator.
// 32 lanes per edge; lane l reads float4 l of the 128-float Q/K rows
// (coalesced 512B per row). 8-lane shfl reduction per head.
// grid = E/8 blocks of 256.
// ---------------------------------------------------------------------------
__global__ __launch_bounds__(256) void att_kernel(
    const float* __restrict__ Q,
    const float* __restrict__ K,
    const int* __restrict__ rows,
    const int* __restrict__ cols,
    float* __restrict__ expAtt,    // [E,4]
    float* __restrict__ attNorm)   // [N,4]
{
    const int e    = blockIdx.x * 8 + (threadIdx.x >> 5);
    const int lane = threadIdx.x & 31;

    const int row = rows[e];
    const int col = cols[e];

    float4 q4 = ((const float4*)Q)[(size_t)row * 32 + lane];
    float4 k4 = ((const float4*)K)[(size_t)col * 32 + lane];
    float p = q4.x * k4.x + q4.y * k4.y + q4.z * k4.z + q4.w * k4.w;

    // reduce within each 8-lane head group
    p += __shfl_down(p, 4, 8);
    p += __shfl_down(p, 2, 8);
    p += __shfl_down(p, 1, 8);

    if ((lane & 7) == 0) {
        const int h = lane >> 3;
        float a  = fminf(fmaxf(p, -10.0f), 10.0f);
        float ea = expf(a);
        expAtt[(size_t)e * HEAD + h] = ea;
        unsafeAtomicAdd(&attNorm[(size_t)row * HEAD + h], ea);
    }
}

// ---------------------------------------------------------------------------
// Kernel 3: normalize + weight V[col] and scatter-add into out[row].
// 32 lanes per edge; lane l handles float4 l of the 128-float V row.
// grid = E/8 blocks of 256.
// ---------------------------------------------------------------------------
__global__ __launch_bounds__(256) void agg_kernel(
    const float* __restrict__ V,
    const int* __restrict__ rows,
    const int* __restrict__ cols,
    const float* __restrict__ expAtt,
    const float* __restrict__ attNorm,
    float* __restrict__ out)
{
    const int e    = blockIdx.x * 8 + (threadIdx.x >> 5);
    const int lane = threadIdx.x & 31;

    const int row = rows[e];
    const int col = cols[e];
    const int h   = lane >> 3;

    const float a = expAtt[(size_t)e * HEAD + h] /
                    (attNorm[(size_t)row * HEAD + h] + 1e-8f);

    float4 v4 = ((const float4*)V)[(size_t)col * 32 + lane];
    float* o = out + (size_t)row * LATDIM + lane * 4;
    unsafeAtomicAdd(o + 0, a * v4.x);
    unsafeAtomicAdd(o + 1, a * v4.y);
    unsafeAtomicAdd(o + 2, a * v4.z);
    unsafeAtomicAdd(o + 3, a * v4.w);
}

// ---------------------------------------------------------------------------
extern "C" void kernel_launch(void* const* d_in, const int* in_sizes, int n_in,
                              void* d_out, int out_size, void* d_ws, size_t ws_size,
                              hipStream_t stream) {
    const float* embeds = (const float*)d_in[0];
    const float* qW     = (const float*)d_in[1];
    const float* kW     = (const float*)d_in[2];
    const float* vW     = (const float*)d_in[3];
    const int*   rows   = (const int*)d_in[4];
    const int*   cols   = (const int*)d_in[5];
    float* out = (float*)d_out;

    // workspace layout (floats):
    //   Q [N*128] | K [N*128] | V [N*128] | expAtt [E*4] | attNorm [N*4]
    float* Q       = (float*)d_ws;
    float* K       = Q + (size_t)N_NODES * LATDIM;
    float* V       = K + (size_t)N_NODES * LATDIM;
    float* expAtt  = V + (size_t)N_NODES * LATDIM;
    float* attNorm = expAtt + (size_t)N_EDGES * HEAD;

    // zero the accumulators (d_out / d_ws are poisoned before every launch)
    hipMemsetAsync(out, 0, sizeof(float) * (size_t)N_NODES * LATDIM, stream);
    hipMemsetAsync(attNorm, 0, sizeof(float) * (size_t)N_NODES * HEAD, stream);

    dim3 pgrid((N_NODES + 63) / 64, 3);
    proj_kernel<<<pgrid, 256, 0, stream>>>(embeds, qW, kW, vW, Q);

    att_kernel<<<N_EDGES / 8, 256, 0, stream>>>(Q, K, rows, cols, expAtt, attNorm);

    agg_kernel<<<N_EDGES / 8, 256, 0, stream>>>(V, rows, cols, expAtt, attNorm, out);
}

// Round 2
// 690.872 us; speedup vs baseline: 2.7190x; 2.7190x over previous
//
#include <hip/hip_runtime.h>
#include <hip/hip_bf16.h>

#define N_NODES 50000
#define N_EDGES 800000
#define LATDIM 128
#define HEAD 4

// ---------------------------------------------------------------------------
// Kernel 1: node projections  P = embeds @ W  for W in {qW, kW, vW}
// (unchanged from round 1 — not the bottleneck yet)
// ---------------------------------------------------------------------------
__global__ __launch_bounds__(256) void proj_kernel(
    const float* __restrict__ embeds,
    const float* __restrict__ qW,
    const float* __restrict__ kW,
    const float* __restrict__ vW,
    float* __restrict__ Pbase)
{
    __shared__ float Wl[128 * 128];

    const int which = blockIdx.y;
    const float* W = (which == 0) ? qW : (which == 1) ? kW : vW;
    float* out = Pbase + (size_t)which * N_NODES * LATDIM;

    const float4* W4 = (const float4*)W;
    float4* Wl4 = (float4*)Wl;
#pragma unroll
    for (int i = 0; i < 16; ++i)
        Wl4[threadIdx.x + 256 * i] = W4[threadIdx.x + 256 * i];
    __syncthreads();

    const int c  = threadIdx.x & 127;
    const int rg = threadIdx.x >> 7;
    const int row0 = blockIdx.x * 64;

    for (int pass = 0; pass < 8; ++pass) {
        const int rbase = row0 + pass * 8 + rg * 4;
        int r0 = rbase + 0, r1 = rbase + 1, r2 = rbase + 2, r3 = rbase + 3;
        int l0 = r0 < N_NODES ? r0 : N_NODES - 1;
        int l1 = r1 < N_NODES ? r1 : N_NODES - 1;
        int l2 = r2 < N_NODES ? r2 : N_NODES - 1;
        int l3 = r3 < N_NODES ? r3 : N_NODES - 1;
        const float4* e0 = (const float4*)(embeds + (size_t)l0 * LATDIM);
        const float4* e1 = (const float4*)(embeds + (size_t)l1 * LATDIM);
        const float4* e2 = (const float4*)(embeds + (size_t)l2 * LATDIM);
        const float4* e3 = (const float4*)(embeds + (size_t)l3 * LATDIM);

        float a0 = 0.f, a1 = 0.f, a2 = 0.f, a3 = 0.f;
#pragma unroll 8
        for (int d4 = 0; d4 < 32; ++d4) {
            float4 x0 = e0[d4];
            float4 x1 = e1[d4];
            float4 x2 = e2[d4];
            float4 x3 = e3[d4];
            float w0 = Wl[(d4 * 4 + 0) * 128 + c];
            float w1 = Wl[(d4 * 4 + 1) * 128 + c];
            float w2 = Wl[(d4 * 4 + 2) * 128 + c];
            float w3 = Wl[(d4 * 4 + 3) * 128 + c];
            a0 += x0.x * w0 + x0.y * w1 + x0.z * w2 + x0.w * w3;
            a1 += x1.x * w0 + x1.y * w1 + x1.z * w2 + x1.w * w3;
            a2 += x2.x * w0 + x2.y * w1 + x2.z * w2 + x2.w * w3;
            a3 += x3.x * w0 + x3.y * w1 + x3.z * w2 + x3.w * w3;
        }
        if (r0 < N_NODES) out[(size_t)r0 * LATDIM + c] = a0;
        if (r1 < N_NODES) out[(size_t)r1 * LATDIM + c] = a1;
        if (r2 < N_NODES) out[(size_t)r2 * LATDIM + c] = a2;
        if (r3 < N_NODES) out[(size_t)r3 * LATDIM + c] = a3;
    }
}

// ---------------------------------------------------------------------------
// CSR build: histogram of rows -> exclusive scan -> scatter cols by row.
// ---------------------------------------------------------------------------
__global__ __launch_bounds__(256) void hist_kernel(
    const int* __restrict__ rows, int* __restrict__ counts)
{
    const int e = blockIdx.x * 256 + threadIdx.x;
    if (e < N_EDGES) atomicAdd(&counts[rows[e]], 1);
}

// Single-workgroup chunked Hillis-Steele exclusive scan over N_NODES counts.
__global__ __launch_bounds__(1024) void scan_kernel(
    const int* __restrict__ counts, int* __restrict__ offsets)
{
    __shared__ int buf[1024];
    const int tid = threadIdx.x;
    int carry = 0;
    const int nchunk = (N_NODES + 1023) / 1024;
    for (int ch = 0; ch < nchunk; ++ch) {
        const int i = ch * 1024 + tid;
        const int v = (i < N_NODES) ? counts[i] : 0;
        buf[tid] = v;
        __syncthreads();
#pragma unroll
        for (int d = 1; d < 1024; d <<= 1) {
            int t = (tid >= d) ? buf[tid - d] : 0;
            __syncthreads();
            buf[tid] += t;
            __syncthreads();
        }
        if (i < N_NODES) offsets[i] = carry + buf[tid] - v;  // exclusive
        carry += buf[1023];
        __syncthreads();
    }
}

__global__ __launch_bounds__(256) void scatter_kernel(
    const int* __restrict__ rows, const int* __restrict__ cols,
    const int* __restrict__ offsets, int* __restrict__ cursor,
    int* __restrict__ sorted_cols)
{
    const int e = blockIdx.x * 256 + threadIdx.x;
    if (e >= N_EDGES) return;
    const int r = rows[e];
    const int p = atomicAdd(&cursor[r], 1);
    sorted_cols[offsets[r] + p] = cols[e];
}

// ---------------------------------------------------------------------------
// Fused attention + aggregation: one wave (64 lanes) per node.
// Lane l owns output dims {2l, 2l+1}; head h = l/16.
// For each incoming edge: gather K[col],V[col] as float2/lane (512B/row,
// coalesced), per-head dot via 4x shfl_xor over the 16-lane head group,
// exp(clip(.)), accumulate numerator and denominator in registers.
// One float2 store per lane at the end. Zero atomics.
// ---------------------------------------------------------------------------
__global__ __launch_bounds__(256) void fused_kernel(
    const float* __restrict__ Q,
    const float* __restrict__ K,
    const float* __restrict__ V,
    const int* __restrict__ offsets,
    const int* __restrict__ counts,
    const int* __restrict__ sorted_cols,
    float* __restrict__ out)
{
    const int n = blockIdx.x * 4 + (threadIdx.x >> 6);
    if (n >= N_NODES) return;
    const int lane = threadIdx.x & 63;

    const float2* Q2 = (const float2*)Q;
    const float2* K2 = (const float2*)K;
    const float2* V2 = (const float2*)V;

    const float2 q = Q2[(size_t)n * 64 + lane];
    const int beg = offsets[n];
    const int deg = counts[n];

    float acc0 = 0.f, acc1 = 0.f, norm = 0.f;

    int i = 0;
    for (; i + 1 < deg; i += 2) {
        const int c0 = sorted_cols[beg + i];
        const int c1 = sorted_cols[beg + i + 1];
        float2 k0 = K2[(size_t)c0 * 64 + lane];
        float2 v0 = V2[(size_t)c0 * 64 + lane];
        float2 k1 = K2[(size_t)c1 * 64 + lane];
        float2 v1 = V2[(size_t)c1 * 64 + lane];

        float p0 = q.x * k0.x + q.y * k0.y;
        float p1 = q.x * k1.x + q.y * k1.y;
        p0 += __shfl_xor(p0, 1);  p1 += __shfl_xor(p1, 1);
        p0 += __shfl_xor(p0, 2);  p1 += __shfl_xor(p1, 2);
        p0 += __shfl_xor(p0, 4);  p1 += __shfl_xor(p1, 4);
        p0 += __shfl_xor(p0, 8);  p1 += __shfl_xor(p1, 8);

        float a0 = expf(fminf(fmaxf(p0, -10.0f), 10.0f));
        float a1 = expf(fminf(fmaxf(p1, -10.0f), 10.0f));
        norm += a0 + a1;
        acc0 += a0 * v0.x + a1 * v1.x;
        acc1 += a0 * v0.y + a1 * v1.y;
    }
    if (i < deg) {
        const int c0 = sorted_cols[beg + i];
        float2 k0 = K2[(size_t)c0 * 64 + lane];
        float2 v0 = V2[(size_t)c0 * 64 + lane];
        float p0 = q.x * k0.x + q.y * k0.y;
        p0 += __shfl_xor(p0, 1);
        p0 += __shfl_xor(p0, 2);
        p0 += __shfl_xor(p0, 4);
        p0 += __shfl_xor(p0, 8);
        float a0 = expf(fminf(fmaxf(p0, -10.0f), 10.0f));
        norm += a0;
        acc0 += a0 * v0.x;
        acc1 += a0 * v0.y;
    }

    const float inv = 1.0f / (norm + 1e-8f);
    ((float2*)out)[(size_t)n * 64 + lane] = make_float2(acc0 * inv, acc1 * inv);
}

// ---------------------------------------------------------------------------
extern "C" void kernel_launch(void* const* d_in, const int* in_sizes, int n_in,
                              void* d_out, int out_size, void* d_ws, size_t ws_size,
                              hipStream_t stream) {
    const float* embeds = (const float*)d_in[0];
    const float* qW     = (const float*)d_in[1];
    const float* kW     = (const float*)d_in[2];
    const float* vW     = (const float*)d_in[3];
    const int*   rows   = (const int*)d_in[4];
    const int*   cols   = (const int*)d_in[5];
    float* out = (float*)d_out;

    // workspace layout:
    //   Q|K|V [3*N*128 f32] | counts[N] | cursor[N] | offsets[N] | sorted_cols[E]
    float* Q = (float*)d_ws;
    float* K = Q + (size_t)N_NODES * LATDIM;
    float* V = K + (size_t)N_NODES * LATDIM;
    int* counts      = (int*)(V + (size_t)N_NODES * LATDIM);
    int* cursor      = counts + N_NODES;
    int* offsets     = cursor + N_NODES;
    int* sorted_cols = offsets + N_NODES;

    // zero counts + cursor (adjacent -> one memset)
    hipMemsetAsync(counts, 0, sizeof(int) * 2 * N_NODES, stream);

    dim3 pgrid((N_NODES + 63) / 64, 3);
    proj_kernel<<<pgrid, 256, 0, stream>>>(embeds, qW, kW, vW, Q);

    hist_kernel<<<(N_EDGES + 255) / 256, 256, 0, stream>>>(rows, counts);
    scan_kernel<<<1, 1024, 0, stream>>>(counts, offsets);
    scatter_kernel<<<(N_EDGES + 255) / 256, 256, 0, stream>>>(
        rows, cols, offsets, cursor, sorted_cols);

    fused_kernel<<<(N_NODES + 3) / 4, 256, 0, stream>>>(
        Q, K, V, offsets, counts, sorted_cols, out);
}

// Round 3
// 503.188 us; speedup vs baseline: 3.7332x; 1.3730x over previous
//
#include <hip/hip_runtime.h>
#include <hip/hip_bf16.h>

#define N_NODES 50000
#define N_EDGES 800000
#define LATDIM 128
#define HEAD 4

// ---------------------------------------------------------------------------
// Kernel 1: node projections  P = embeds @ W  for W in {qW, kW, vW}
// Round-3 restructure for occupancy:
//   - 16 KB LDS (32-row chunk of W), 4 chunks per block
//   - 16 output rows per block (128 cols x 2 row-groups x 8 rows)
//   - per chunk: W column staged LDS->32 registers, reused across 8 rows
//   - embeds reads are wave-uniform -> forced scalar via readfirstlane
// grid = (N/16, 3); N_NODES % 16 == 0 so no bounds checks.
// ---------------------------------------------------------------------------
__global__ __launch_bounds__(256) void proj_kernel(
    const float* __restrict__ embeds,
    const float* __restrict__ qW,
    const float* __restrict__ kW,
    const float* __restrict__ vW,
    float* __restrict__ Pbase)
{
    __shared__ float Wl[32 * 128];   // 16 KB

    const int which = blockIdx.y;
    const float* W = (which == 0) ? qW : (which == 1) ? kW : vW;
    float* out = Pbase + (size_t)which * N_NODES * LATDIM;

    const int c  = threadIdx.x & 127;          // output column
    const int rg = threadIdx.x >> 7;           // row-group 0/1
    // wave-uniform base row for this row-group (8 rows)
    const int row0 = __builtin_amdgcn_readfirstlane(blockIdx.x * 16 + rg * 8);

    const float4* E4 = (const float4*)embeds;  // row stride = 32 float4

    float acc[8] = {0.f, 0.f, 0.f, 0.f, 0.f, 0.f, 0.f, 0.f};

    for (int ch = 0; ch < 4; ++ch) {
        __syncthreads();  // previous chunk's Wl reads complete
        // stage W rows [ch*32, ch*32+32): 4096 floats = 1024 float4
        const float4* Wsrc = (const float4*)W + ch * 1024;
        float4* Wl4 = (float4*)Wl;
#pragma unroll
        for (int i = 0; i < 4; ++i)
            Wl4[threadIdx.x + 256 * i] = Wsrc[threadIdx.x + 256 * i];
        __syncthreads();

        // preload this thread's W column chunk (32 values, reused x8 rows)
        float w[32];
#pragma unroll
        for (int j = 0; j < 32; ++j)
            w[j] = Wl[j * 128 + c];

#pragma unroll
        for (int d4 = 0; d4 < 8; ++d4) {
#pragma unroll
            for (int r = 0; r < 8; ++r) {
                float4 x = E4[(size_t)(row0 + r) * 32 + ch * 8 + d4];
                acc[r] += x.x * w[d4 * 4 + 0] + x.y * w[d4 * 4 + 1] +
                          x.z * w[d4 * 4 + 2] + x.w * w[d4 * 4 + 3];
            }
        }
    }

#pragma unroll
    for (int r = 0; r < 8; ++r)
        out[(size_t)(row0 + r) * LATDIM + c] = acc[r];
}

// ---------------------------------------------------------------------------
// CSR build: histogram of rows -> exclusive scan -> scatter cols by row.
// ---------------------------------------------------------------------------
__global__ __launch_bounds__(256) void hist_kernel(
    const int* __restrict__ rows, int* __restrict__ counts)
{
    const int e = blockIdx.x * 256 + threadIdx.x;
    if (e < N_EDGES) atomicAdd(&counts[rows[e]], 1);
}

// Single-workgroup scan: wave shfl-scan + cross-wave LDS scan (3 barriers/chunk).
__global__ __launch_bounds__(1024) void scan_kernel(
    const int* __restrict__ counts, int* __restrict__ offsets)
{
    __shared__ int ws[16];
    __shared__ int wtot;
    const int tid  = threadIdx.x;
    const int wid  = tid >> 6;
    const int lane = tid & 63;
    int carry = 0;
    const int nchunk = (N_NODES + 1023) / 1024;
    for (int ch = 0; ch < nchunk; ++ch) {
        const int i = ch * 1024 + tid;
        const int x = (i < N_NODES) ? counts[i] : 0;
        int s = x;  // inclusive wave scan
#pragma unroll
        for (int d = 1; d < 64; d <<= 1) {
            int t = __shfl_up(s, d, 64);
            if (lane >= d) s += t;
        }
        if (lane == 63) ws[wid] = s;
        __syncthreads();
        if (tid == 0) {
            int run = 0;
#pragma unroll
            for (int j = 0; j < 16; ++j) { int t = ws[j]; ws[j] = run; run += t; }
            wtot = run;
        }
        __syncthreads();
        if (i < N_NODES) offsets[i] = carry + ws[wid] + (s - x);  // exclusive
        carry += wtot;
        __syncthreads();  // protect ws before next chunk overwrites
    }
}

__global__ __launch_bounds__(256) void scatter_kernel(
    const int* __restrict__ rows, const int* __restrict__ cols,
    const int* __restrict__ offsets, int* __restrict__ cursor,
    int* __restrict__ sorted_cols)
{
    const int e = blockIdx.x * 256 + threadIdx.x;
    if (e >= N_EDGES) return;
    const int r = rows[e];
    const int p = atomicAdd(&cursor[r], 1);
    sorted_cols[offsets[r] + p] = cols[e];
}

// ---------------------------------------------------------------------------
// Fused attention + aggregation: one wave (64 lanes) per node. (unchanged)
// ---------------------------------------------------------------------------
__global__ __launch_bounds__(256) void fused_kernel(
    const float* __restrict__ Q,
    const float* __restrict__ K,
    const float* __restrict__ V,
    const int* __restrict__ offsets,
    const int* __restrict__ counts,
    const int* __restrict__ sorted_cols,
    float* __restrict__ out)
{
    const int n = blockIdx.x * 4 + (threadIdx.x >> 6);
    if (n >= N_NODES) return;
    const int lane = threadIdx.x & 63;

    const float2* Q2 = (const float2*)Q;
    const float2* K2 = (const float2*)K;
    const float2* V2 = (const float2*)V;

    const float2 q = Q2[(size_t)n * 64 + lane];
    const int beg = offsets[n];
    const int deg = counts[n];

    float acc0 = 0.f, acc1 = 0.f, norm = 0.f;

    int i = 0;
    for (; i + 1 < deg; i += 2) {
        const int c0 = sorted_cols[beg + i];
        const int c1 = sorted_cols[beg + i + 1];
        float2 k0 = K2[(size_t)c0 * 64 + lane];
        float2 v0 = V2[(size_t)c0 * 64 + lane];
        float2 k1 = K2[(size_t)c1 * 64 + lane];
        float2 v1 = V2[(size_t)c1 * 64 + lane];

        float p0 = q.x * k0.x + q.y * k0.y;
        float p1 = q.x * k1.x + q.y * k1.y;
        p0 += __shfl_xor(p0, 1);  p1 += __shfl_xor(p1, 1);
        p0 += __shfl_xor(p0, 2);  p1 += __shfl_xor(p1, 2);
        p0 += __shfl_xor(p0, 4);  p1 += __shfl_xor(p1, 4);
        p0 += __shfl_xor(p0, 8);  p1 += __shfl_xor(p1, 8);

        float a0 = expf(fminf(fmaxf(p0, -10.0f), 10.0f));
        float a1 = expf(fminf(fmaxf(p1, -10.0f), 10.0f));
        norm += a0 + a1;
        acc0 += a0 * v0.x + a1 * v1.x;
        acc1 += a0 * v0.y + a1 * v1.y;
    }
    if (i < deg) {
        const int c0 = sorted_cols[beg + i];
        float2 k0 = K2[(size_t)c0 * 64 + lane];
        float2 v0 = V2[(size_t)c0 * 64 + lane];
        float p0 = q.x * k0.x + q.y * k0.y;
        p0 += __shfl_xor(p0, 1);
        p0 += __shfl_xor(p0, 2);
        p0 += __shfl_xor(p0, 4);
        p0 += __shfl_xor(p0, 8);
        float a0 = expf(fminf(fmaxf(p0, -10.0f), 10.0f));
        norm += a0;
        acc0 += a0 * v0.x;
        acc1 += a0 * v0.y;
    }

    const float inv = 1.0f / (norm + 1e-8f);
    ((float2*)out)[(size_t)n * 64 + lane] = make_float2(acc0 * inv, acc1 * inv);
}

// ---------------------------------------------------------------------------
extern "C" void kernel_launch(void* const* d_in, const int* in_sizes, int n_in,
                              void* d_out, int out_size, void* d_ws, size_t ws_size,
                              hipStream_t stream) {
    const float* embeds = (const float*)d_in[0];
    const float* qW     = (const float*)d_in[1];
    const float* kW     = (const float*)d_in[2];
    const float* vW     = (const float*)d_in[3];
    const int*   rows   = (const int*)d_in[4];
    const int*   cols   = (const int*)d_in[5];
    float* out = (float*)d_out;

    // workspace layout:
    //   Q|K|V [3*N*128 f32] | counts[N] | cursor[N] | offsets[N] | sorted_cols[E]
    float* Q = (float*)d_ws;
    float* K = Q + (size_t)N_NODES * LATDIM;
    float* V = K + (size_t)N_NODES * LATDIM;
    int* counts      = (int*)(V + (size_t)N_NODES * LATDIM);
    int* cursor      = counts + N_NODES;
    int* offsets     = cursor + N_NODES;
    int* sorted_cols = offsets + N_NODES;

    // zero counts + cursor (adjacent -> one memset). out needs no memset:
    // fused_kernel stores every element.
    hipMemsetAsync(counts, 0, sizeof(int) * 2 * N_NODES, stream);

    dim3 pgrid(N_NODES / 16, 3);
    proj_kernel<<<pgrid, 256, 0, stream>>>(embeds, qW, kW, vW, Q);

    hist_kernel<<<(N_EDGES + 255) / 256, 256, 0, stream>>>(rows, counts);
    scan_kernel<<<1, 1024, 0, stream>>>(counts, offsets);
    scatter_kernel<<<(N_EDGES + 255) / 256, 256, 0, stream>>>(
        rows, cols, offsets, cursor, sorted_cols);

    fused_kernel<<<(N_NODES + 3) / 4, 256, 0, stream>>>(
        Q, K, V, offsets, counts, sorted_cols, out);
}

// Round 4
// 368.150 us; speedup vs baseline: 5.1025x; 1.3668x over previous
//
#include <hip/hip_runtime.h>
#include <hip/hip_bf16.h>

#define N_NODES 50000
#define N_EDGES 800000
#define LATDIM 128
#define HEAD 4

typedef __attribute__((ext_vector_type(8))) short short8;
typedef __attribute__((ext_vector_type(4))) float floatx4;

// ---------------------------------------------------------------------------
// fp32 -> bf16 hi/lo split helpers (RNE via bit math; inputs are finite)
// ---------------------------------------------------------------------------
__device__ __forceinline__ unsigned bf16_rne_bits(float x) {
    unsigned u = __builtin_bit_cast(unsigned, x);
    return (u + 0x7fffu + ((u >> 16) & 1u)) & 0xffff0000u;
}
__device__ __forceinline__ void split_bf16(float x, short& hi, short& lo) {
    unsigned hb = bf16_rne_bits(x);
    hi = (short)(hb >> 16);
    float hf = __builtin_bit_cast(float, hb);
    unsigned lb = bf16_rne_bits(x - hf);
    lo = (short)(lb >> 16);
}

// ---------------------------------------------------------------------------
// Convert embeds (fp32, row-major [N][128]) -> Ehi, Elo (bf16 as short).
// One thread per 8 elements. 6.4M/8 = 800000 threads.
// ---------------------------------------------------------------------------
__global__ __launch_bounds__(256) void convert_kernel(
    const float* __restrict__ E, short* __restrict__ Ehi, short* __restrict__ Elo)
{
    const size_t t = (size_t)blockIdx.x * 256 + threadIdx.x;
    const size_t base = t * 8;
    float4 a = ((const float4*)E)[t * 2 + 0];
    float4 b = ((const float4*)E)[t * 2 + 1];
    float x[8] = {a.x, a.y, a.z, a.w, b.x, b.y, b.z, b.w};
    short hi[8], lo[8];
#pragma unroll
    for (int i = 0; i < 8; ++i) split_bf16(x[i], hi[i], lo[i]);
    *(short8*)(Ehi + base) = *(short8*)hi;
    *(short8*)(Elo + base) = *(short8*)lo;
}

// ---------------------------------------------------------------------------
// Pack W (fp32 [128][128], k-major) into B-fragment order, hi/lo bf16:
//   Wpack[ ((chunk*128 + n)*4 + quad)*8 + j ] = W[chunk*32 + quad*8 + j][n]
// so a lane's 8-element B fragment is one contiguous 16-B load.
// grid = (64, 3): 16384 threads per projection, one per (k,n).
// ---------------------------------------------------------------------------
__global__ __launch_bounds__(256) void packW_kernel(
    const float* __restrict__ qW, const float* __restrict__ kW,
    const float* __restrict__ vW, short* __restrict__ WhiBase,
    short* __restrict__ WloBase)
{
    const int which = blockIdx.y;
    const float* W = (which == 0) ? qW : (which == 1) ? kW : vW;
    short* Whi = WhiBase + which * 16384;
    short* Wlo = WloBase + which * 16384;

    const int t = blockIdx.x * 256 + threadIdx.x;  // [0, 16384)
    const int k = t >> 7, n = t & 127;
    const int c = k >> 5, q = (k >> 3) & 3, j = k & 7;
    short hi, lo;
    split_bf16(W[k * 128 + n], hi, lo);
    const int dst = ((c * 128 + n) * 4 + q) * 8 + j;
    Whi[dst] = hi;
    Wlo[dst] = lo;
}

// ---------------------------------------------------------------------------
// MFMA projection GEMM: P = E @ W, fp32-accurate via 3-term hi/lo split.
// Block = 4 waves; wave w owns 32-col stripe (2 col-tiles), B frags in regs.
// Block covers 128 rows = 8 row-tiles of 16. grid = (ceil(N/128), 3).
// mfma_f32_16x16x32_bf16: A[m=lane&15][k=q*8+j], B[k=q*8+j][n=lane&15],
// D: col=lane&15, row=q*4+reg.
// ---------------------------------------------------------------------------
__global__ __launch_bounds__(256) void gemm_kernel(
    const short* __restrict__ Ehi, const short* __restrict__ Elo,
    const short* __restrict__ WhiBase, const short* __restrict__ WloBase,
    float* __restrict__ Pbase)
{
    const int which = blockIdx.y;
    const short* Whi = WhiBase + which * 16384;
    const short* Wlo = WloBase + which * 16384;
    float* out = Pbase + (size_t)which * N_NODES * LATDIM;

    const int wave = threadIdx.x >> 6;
    const int lane = threadIdx.x & 63;
    const int ln = lane & 15;
    const int q  = lane >> 4;
    const int n_base = wave * 32;

    // Load B fragments once: 2 col-tiles x 4 k-chunks x {hi,lo}
    short8 Bh[2][4], Bl[2][4];
#pragma unroll
    for (int tIdx = 0; tIdx < 2; ++tIdx)
#pragma unroll
        for (int c = 0; c < 4; ++c) {
            const int off = ((c * 128 + n_base + tIdx * 16 + ln) * 4 + q) * 8;
            Bh[tIdx][c] = *(const short8*)(Whi + off);
            Bl[tIdx][c] = *(const short8*)(Wlo + off);
        }

    const int r_base = blockIdx.x * 128;

    for (int rt = 0; rt < 8; ++rt) {
        const int r0 = r_base + rt * 16;
        int rowm = r0 + ln;
        if (rowm > N_NODES - 1) rowm = N_NODES - 1;
        const short* eh = Ehi + (size_t)rowm * 128 + q * 8;
        const short* el = Elo + (size_t)rowm * 128 + q * 8;

        floatx4 acc0 = {0.f, 0.f, 0.f, 0.f};
        floatx4 acc1 = {0.f, 0.f, 0.f, 0.f};
#pragma unroll
        for (int c = 0; c < 4; ++c) {
            short8 Ah = *(const short8*)(eh + c * 32);
            short8 Al = *(const short8*)(el + c * 32);
            acc0 = __builtin_amdgcn_mfma_f32_16x16x32_bf16(Ah, Bh[0][c], acc0, 0, 0, 0);
            acc0 = __builtin_amdgcn_mfma_f32_16x16x32_bf16(Ah, Bl[0][c], acc0, 0, 0, 0);
            acc0 = __builtin_amdgcn_mfma_f32_16x16x32_bf16(Al, Bh[0][c], acc0, 0, 0, 0);
            acc1 = __builtin_amdgcn_mfma_f32_16x16x32_bf16(Ah, Bh[1][c], acc1, 0, 0, 0);
            acc1 = __builtin_amdgcn_mfma_f32_16x16x32_bf16(Ah, Bl[1][c], acc1, 0, 0, 0);
            acc1 = __builtin_amdgcn_mfma_f32_16x16x32_bf16(Al, Bh[1][c], acc1, 0, 0, 0);
        }

#pragma unroll
        for (int r = 0; r < 4; ++r) {
            const int row = r0 + q * 4 + r;
            if (row < N_NODES) {
                out[(size_t)row * 128 + n_base + ln]      = acc0[r];
                out[(size_t)row * 128 + n_base + 16 + ln] = acc1[r];
            }
        }
    }
}

// ---------------------------------------------------------------------------
// CSR build: histogram -> scan -> scatter (unchanged from round 3)
// ---------------------------------------------------------------------------
__global__ __launch_bounds__(256) void hist_kernel(
    const int* __restrict__ rows, int* __restrict__ counts)
{
    const int e = blockIdx.x * 256 + threadIdx.x;
    if (e < N_EDGES) atomicAdd(&counts[rows[e]], 1);
}

__global__ __launch_bounds__(1024) void scan_kernel(
    const int* __restrict__ counts, int* __restrict__ offsets)
{
    __shared__ int ws[16];
    __shared__ int wtot;
    const int tid  = threadIdx.x;
    const int wid  = tid >> 6;
    const int lane = tid & 63;
    int carry = 0;
    const int nchunk = (N_NODES + 1023) / 1024;
    for (int ch = 0; ch < nchunk; ++ch) {
        const int i = ch * 1024 + tid;
        const int x = (i < N_NODES) ? counts[i] : 0;
        int s = x;
#pragma unroll
        for (int d = 1; d < 64; d <<= 1) {
            int t = __shfl_up(s, d, 64);
            if (lane >= d) s += t;
        }
        if (lane == 63) ws[wid] = s;
        __syncthreads();
        if (tid == 0) {
            int run = 0;
#pragma unroll
            for (int j = 0; j < 16; ++j) { int t = ws[j]; ws[j] = run; run += t; }
            wtot = run;
        }
        __syncthreads();
        if (i < N_NODES) offsets[i] = carry + ws[wid] + (s - x);
        carry += wtot;
        __syncthreads();
    }
}

__global__ __launch_bounds__(256) void scatter_kernel(
    const int* __restrict__ rows, const int* __restrict__ cols,
    const int* __restrict__ offsets, int* __restrict__ cursor,
    int* __restrict__ sorted_cols)
{
    const int e = blockIdx.x * 256 + threadIdx.x;
    if (e >= N_EDGES) return;
    const int r = rows[e];
    const int p = atomicAdd(&cursor[r], 1);
    sorted_cols[offsets[r] + p] = cols[e];
}

// ---------------------------------------------------------------------------
// Fused attention + aggregation: one wave per node (unchanged from round 3)
// ---------------------------------------------------------------------------
__global__ __launch_bounds__(256) void fused_kernel(
    const float* __restrict__ Q,
    const float* __restrict__ K,
    const float* __restrict__ V,
    const int* __restrict__ offsets,
    const int* __restrict__ counts,
    const int* __restrict__ sorted_cols,
    float* __restrict__ out)
{
    const int n = blockIdx.x * 4 + (threadIdx.x >> 6);
    if (n >= N_NODES) return;
    const int lane = threadIdx.x & 63;

    const float2* Q2 = (const float2*)Q;
    const float2* K2 = (const float2*)K;
    const float2* V2 = (const float2*)V;

    const float2 q = Q2[(size_t)n * 64 + lane];
    const int beg = offsets[n];
    const int deg = counts[n];

    float acc0 = 0.f, acc1 = 0.f, norm = 0.f;

    int i = 0;
    for (; i + 1 < deg; i += 2) {
        const int c0 = sorted_cols[beg + i];
        const int c1 = sorted_cols[beg + i + 1];
        float2 k0 = K2[(size_t)c0 * 64 + lane];
        float2 v0 = V2[(size_t)c0 * 64 + lane];
        float2 k1 = K2[(size_t)c1 * 64 + lane];
        float2 v1 = V2[(size_t)c1 * 64 + lane];

        float p0 = q.x * k0.x + q.y * k0.y;
        float p1 = q.x * k1.x + q.y * k1.y;
        p0 += __shfl_xor(p0, 1);  p1 += __shfl_xor(p1, 1);
        p0 += __shfl_xor(p0, 2);  p1 += __shfl_xor(p1, 2);
        p0 += __shfl_xor(p0, 4);  p1 += __shfl_xor(p1, 4);
        p0 += __shfl_xor(p0, 8);  p1 += __shfl_xor(p1, 8);

        float a0 = expf(fminf(fmaxf(p0, -10.0f), 10.0f));
        float a1 = expf(fminf(fmaxf(p1, -10.0f), 10.0f));
        norm += a0 + a1;
        acc0 += a0 * v0.x + a1 * v1.x;
        acc1 += a0 * v0.y + a1 * v1.y;
    }
    if (i < deg) {
        const int c0 = sorted_cols[beg + i];
        float2 k0 = K2[(size_t)c0 * 64 + lane];
        float2 v0 = V2[(size_t)c0 * 64 + lane];
        float p0 = q.x * k0.x + q.y * k0.y;
        p0 += __shfl_xor(p0, 1);
        p0 += __shfl_xor(p0, 2);
        p0 += __shfl_xor(p0, 4);
        p0 += __shfl_xor(p0, 8);
        float a0 = expf(fminf(fmaxf(p0, -10.0f), 10.0f));
        norm += a0;
        acc0 += a0 * v0.x;
        acc1 += a0 * v0.y;
    }

    const float inv = 1.0f / (norm + 1e-8f);
    ((float2*)out)[(size_t)n * 64 + lane] = make_float2(acc0 * inv, acc1 * inv);
}

// ---------------------------------------------------------------------------
extern "C" void kernel_launch(void* const* d_in, const int* in_sizes, int n_in,
                              void* d_out, int out_size, void* d_ws, size_t ws_size,
                              hipStream_t stream) {
    const float* embeds = (const float*)d_in[0];
    const float* qW     = (const float*)d_in[1];
    const float* kW     = (const float*)d_in[2];
    const float* vW     = (const float*)d_in[3];
    const int*   rows   = (const int*)d_in[4];
    const int*   cols   = (const int*)d_in[5];
    float* out = (float*)d_out;

    // workspace layout (floats unless noted):
    //   Q|K|V [3*N*128 f32] | counts[N] | cursor[N] | offsets[N] |
    //   sorted_cols[E] | Ehi[N*128 bf16] | Elo[N*128 bf16] |
    //   Whi[3*16384 bf16] | Wlo[3*16384 bf16]
    float* Q = (float*)d_ws;
    float* K = Q + (size_t)N_NODES * LATDIM;
    float* V = K + (size_t)N_NODES * LATDIM;
    int* counts      = (int*)(V + (size_t)N_NODES * LATDIM);
    int* cursor      = counts + N_NODES;
    int* offsets     = cursor + N_NODES;
    int* sorted_cols = offsets + N_NODES;
    short* Ehi = (short*)(sorted_cols + N_EDGES);
    short* Elo = Ehi + (size_t)N_NODES * LATDIM;
    short* Whi = Elo + (size_t)N_NODES * LATDIM;
    short* Wlo = Whi + 3 * 16384;

    hipMemsetAsync(counts, 0, sizeof(int) * 2 * N_NODES, stream);

    convert_kernel<<<(N_NODES * LATDIM / 8 + 255) / 256, 256, 0, stream>>>(
        embeds, Ehi, Elo);
    packW_kernel<<<dim3(64, 3), 256, 0, stream>>>(qW, kW, vW, Whi, Wlo);

    gemm_kernel<<<dim3((N_NODES + 127) / 128, 3), 256, 0, stream>>>(
        Ehi, Elo, Whi, Wlo, Q);

    hist_kernel<<<(N_EDGES + 255) / 256, 256, 0, stream>>>(rows, counts);
    scan_kernel<<<1, 1024, 0, stream>>>(counts, offsets);
    scatter_kernel<<<(N_EDGES + 255) / 256, 256, 0, stream>>>(
        rows, cols, offsets, cursor, sorted_cols);

    fused_kernel<<<(N_NODES + 3) / 4, 256, 0, stream>>>(
        Q, K, V, offsets, counts, sorted_cols, out);
}